// Round 20
// baseline (429.094 us; speedup 1.0000x reference)
//
#include <hip/hip_runtime.h>
#include <hip/hip_fp16.h>

#define DT 0.1f
#define NSTEPS 10

typedef float f4 __attribute__((ext_vector_type(4)));
typedef __fp16 h2 __attribute__((ext_vector_type(2)));
typedef __fp16 h4 __attribute__((ext_vector_type(4)));

// MFMA builtin exists only in the device pass; host pass just needs to parse.
#if defined(__HIP_DEVICE_COMPILE__)
  #if __has_builtin(__builtin_amdgcn_mfma_f32_16x16x16f16)
    #define MFMA16(A, B, C) __builtin_amdgcn_mfma_f32_16x16x16f16((A), (B), (C), 0, 0, 0)
  #else
    #define MFMA16(A, B, C) __builtin_amdgcn_mfma_f32_16x16x16_f16((A), (B), (C), 0, 0, 0)
  #endif
  #define SQRTF(x) __builtin_amdgcn_sqrtf(x)
  #define EXP2F(x) __builtin_amdgcn_exp2f(x)
  #define RCPF(x)  __builtin_amdgcn_rcpf(x)
#else
  #define MFMA16(A, B, C) ((void)(A), (void)(B), (C))
  #define SQRTF(x) sqrtf(x)
  #define EXP2F(x) exp2f(x)
  #define RCPF(x)  (1.0f / (x))
#endif

// f32 exp-form tanh on the 4 f32 accumulator values, ONE hardware rcp
// (shared 4-way), exact saturation. Clamp +-5: tanh(5)=0.999909 (tail err
// 9.1e-5); e^(2x) <= 22737, 4-way product <= 2.7e17 — no overflow, no NaN.
// Output packed as h4 ready to be the next MFMA's B operand.
static __device__ __forceinline__ h4 act_h4(f4 v) {
    float x0 = fminf(fmaxf(v[0], -5.0f), 5.0f);
    float x1 = fminf(fmaxf(v[1], -5.0f), 5.0f);
    float x2 = fminf(fmaxf(v[2], -5.0f), 5.0f);
    float x3 = fminf(fmaxf(v[3], -5.0f), 5.0f);
    float e0 = EXP2F(x0 * 2.8853900818f);
    float e1 = EXP2F(x1 * 2.8853900818f);
    float e2 = EXP2F(x2 * 2.8853900818f);
    float e3 = EXP2F(x3 * 2.8853900818f);
    float q0 = e0 + 1.0f, q1 = e1 + 1.0f, q2 = e2 + 1.0f, q3 = e3 + 1.0f;
    float p01 = q0 * q1;
    float p23 = q2 * q3;
    float R = RCPF(p01 * p23);
    float r01 = R * p23;              // 1/(q0*q1)
    float r23 = R * p01;              // 1/(q2*q3)
    float t0 = fmaf(r01 * q1, -2.0f, 1.0f);   // 1 - 2/q0 = tanh(x0)
    float t1 = fmaf(r01 * q0, -2.0f, 1.0f);
    float t2 = fmaf(r23 * q3, -2.0f, 1.0f);
    float t3 = fmaf(r23 * q2, -2.0f, 1.0f);
    h2 a = __builtin_bit_cast(h2, __floats2half2_rn(t0, t1));
    h2 b = __builtin_bit_cast(h2, __floats2half2_rn(t2, t3));
    h4 r;
    r[0] = a[0]; r[1] = a[1]; r[2] = b[0]; r[3] = b[1];
    return r;
}

__global__ void __launch_bounds__(256) rollout_kernel(
    const float* __restrict__ s_star, const float* __restrict__ s0,
    const float* __restrict__ fc1_w, const float* __restrict__ fc1_b,
    const float* __restrict__ fc2_w, const float* __restrict__ fc2_b,
    const float* __restrict__ rc1_w, const float* __restrict__ rc1_b,
    const float* __restrict__ rc2_w, const float* __restrict__ rc2_b,
    const float* __restrict__ rc3_w, const float* __restrict__ rc3_b,
    const float* __restrict__ rr1_w, const float* __restrict__ rr1_b,
    const float* __restrict__ rr2_w, const float* __restrict__ rr2_b,
    const float* __restrict__ rr3_w, const float* __restrict__ rr3_b,
    float* __restrict__ out, int NW)   // NW = B/128 waves
{
    int lane = threadIdx.x & 63;
    int wid  = threadIdx.x >> 6;
    int wave = blockIdx.x * 4 + wid;
    if (wave >= NW) return;

    int col = lane & 15;                // batch column within each 16-row chunk
    int kg  = lane >> 4;                // k-group / chunk ownership 0..3
    int rA  = col;                      // A-fragment row for this lane
    int rowA = wave * 128 + lane;       // set 0 row
    int rowB = rowA + 64;               // set 1 row

    // ---- uniform fused predictor: ah = A @ [s, s_star] + cb ----
    float A[2][4];
    float cb[2];
#pragma unroll
    for (int r = 0; r < 2; ++r) {
#pragma unroll
        for (int c = 0; c < 4; ++c) {
            float a = 0.0f;
#pragma unroll
            for (int j = 0; j < 4; ++j)
                a = fmaf(fc2_w[r * 4 + j], fc1_w[j * 4 + c], a);
            A[r][c] = a;
        }
        float b = fc2_b[r];
#pragma unroll
        for (int j = 0; j < 4; ++j) b = fmaf(fc2_w[r * 4 + j], fc1_b[j], b);
        cb[r] = b;
    }

    // ---- per-lane state, 2 row-sets ----
    float ssx[2], ssy[2], sx[2], sy[2], d0[2], d1[2], ahs0[2], err[2];
    {
        float2 sA = reinterpret_cast<const float2*>(s_star)[rowA];
        float2 sB = reinterpret_cast<const float2*>(s_star)[rowB];
        float2 vA = reinterpret_cast<const float2*>(s0)[rowA];
        float2 vB = reinterpret_cast<const float2*>(s0)[rowB];
        ssx[0] = sA.x; ssy[0] = sA.y; sx[0] = vA.x; sy[0] = vA.y;
        ssx[1] = sB.x; ssy[1] = sB.y; sx[1] = vB.x; sy[1] = vB.y;
    }
#pragma unroll
    for (int s = 0; s < 2; ++s) {
        d0[s] = fmaf(A[0][2], ssx[s], fmaf(A[0][3], ssy[s], cb[0]));
        d1[s] = fmaf(A[1][2], ssx[s], fmaf(A[1][3], ssy[s], cb[1]));
        ahs0[s] = (ssx[s] > 0.5f) ? -1.0f : 1.0f;
        err[s] = 0.0f;
    }

    h4 zero4; zero4[0] = (__fp16)0.0f; zero4[1] = (__fp16)0.0f;
    zero4[2] = (__fp16)0.0f; zero4[3] = (__fp16)0.0f;

    // ---- A1: raw W1 rows (0-7 rr, 8-15 rc), masked per chunk (loop-invariant) ----
    int jr = rA & 7;
    const float* w1p = (rA < 8) ? rr1_w : rc1_w;
    h4 A1raw;
#pragma unroll
    for (int j = 0; j < 4; ++j) A1raw[j] = (__fp16)w1p[jr * 4 + j];
    h4 A1m[4];
#pragma unroll
    for (int q = 0; q < 4; ++q) A1m[q] = (kg == q) ? A1raw : zero4;

    // ---- A2: block-diag(W2rr, W2rc), shared by all chunks ----
    h4 A2;
#pragma unroll
    for (int j = 0; j < 4; ++j) {
        int k = 4 * kg + j;
        float v = 0.0f;
        if (rA < 8) { if (k < 8) v = rr2_w[rA * 8 + k]; }
        else        { if (k >= 8) v = rc2_w[(rA - 8) * 8 + (k - 8)]; }
        A2[j] = (__fp16)v;
    }

    // ---- A3: per-chunk fragments (chunk q outputs -> rows 4q..4q+3) ----
    int qstar = rA >> 2;
    int o = rA & 3;
    h4 A3own;
#pragma unroll
    for (int j = 0; j < 4; ++j) {
        int k = 4 * kg + j;
        float v = 0.0f;
        if (o < 2) { if (k < 8)  v = rr3_w[o * 8 + k]; }
        else       { if (k >= 8) v = rc3_w[(o - 2) * 8 + (k - 8)]; }
        A3own[j] = (__fp16)v;
    }
    h4 A3f[4];
#pragma unroll
    for (int q = 0; q < 4; ++q) A3f[q] = (qstar == q) ? A3own : zero4;

    // ---- C operands (f32; C/D row = 4*kg+reg, col = lane&15) ----
    f4 C1, C2, C3;
#pragma unroll
    for (int j = 0; j < 4; ++j) {
        int r4 = 4 * kg + j;
        C1[j] = (r4 < 8) ? rr1_b[r4] : rc1_b[r4 - 8];
        C2[j] = (r4 < 8) ? rr2_b[r4] : rc2_b[r4 - 8];
    }
    C3[0] = rr3_b[0]; C3[1] = rr3_b[1]; C3[2] = rc3_b[0]; C3[3] = rc3_b[1];

#pragma unroll 1
    for (int t = 0; t < NSTEPS; ++t) {
        float ah0[2], ah1[2];
        h4 Bown[2];
#pragma unroll
        for (int s = 0; s < 2; ++s) {
            ah0[s] = fmaf(A[0][0], sx[s], fmaf(A[0][1], sy[s], d0[s]));
            ah1[s] = fmaf(A[1][0], sx[s], fmaf(A[1][1], sy[s], d1[s]));
            h2 lo = __builtin_bit_cast(h2, __floats2half2_rn(sx[s], sy[s]));
            h2 hi = __builtin_bit_cast(h2, __floats2half2_rn(ah0[s], ah1[s]));
            Bown[s][0] = lo[0]; Bown[s][1] = lo[1];
            Bown[s][2] = hi[0]; Bown[s][3] = hi[1];
        }

        // L1: 8 independent MFMAs (A-masked, unmasked own-state B)
        h4 B2[2][4];
#pragma unroll
        for (int s = 0; s < 2; ++s) {
#pragma unroll
            for (int q = 0; q < 4; ++q) {
                f4 D1 = MFMA16(A1m[q], Bown[s], C1);
                B2[s][q] = act_h4(D1);
            }
        }

        // L2: 8 independent MFMAs
        h4 B3[2][4];
#pragma unroll
        for (int s = 0; s < 2; ++s) {
#pragma unroll
            for (int q = 0; q < 4; ++q) {
                f4 D2 = MFMA16(A2, B2[s][q], C2);
                B3[s][q] = act_h4(D2);
            }
        }

        // L3: per-set accumulator chain over disjoint row-blocks
#pragma unroll
        for (int s = 0; s < 2; ++s) {
            f4 D3 = MFMA16(A3f[0], B3[s][0], C3);
            D3 = MFMA16(A3f[1], B3[s][1], D3);
            D3 = MFMA16(A3f[2], B3[s][2], D3);
            D3 = MFMA16(A3f[3], B3[s][3], D3);

            float arr0 = D3[0], arr1 = D3[1], ar0 = D3[2], ar1 = D3[3];

            sx[s] = fmaf(DT, ar0, sx[s]);
            sy[s] = fmaf(DT, ar1, sy[s]);

            float dx = ssx[s] - sx[s], dy = ssy[s] - sy[s];
            float n1 = fmaf(dx, dx, dy * dy);
            float ux = arr0 - ar0, uy = arr1 - ar1;
            float n2 = fmaf(ux, ux, uy * uy);
            float vx = ahs0[s] - ah0[s];
            float n3 = fmaf(vx, vx, ah1[s] * ah1[s]);

            err[s] = err[s] + SQRTF(n1);
            err[s] = fmaf(0.1f, SQRTF(n2), err[s]);
            err[s] = err[s] + SQRTF(n3);
        }
    }

    out[rowA] = err[0];
    out[rowB] = err[1];
}

extern "C" void kernel_launch(void* const* d_in, const int* in_sizes, int n_in,
                              void* d_out, int out_size, void* d_ws, size_t ws_size,
                              hipStream_t stream) {
    const float* s_star = (const float*)d_in[0];
    const float* s0     = (const float*)d_in[1];
    const float* fc1_w  = (const float*)d_in[2];
    const float* fc1_b  = (const float*)d_in[3];
    const float* fc2_w  = (const float*)d_in[4];
    const float* fc2_b  = (const float*)d_in[5];
    const float* rc1_w  = (const float*)d_in[6];
    const float* rc1_b  = (const float*)d_in[7];
    const float* rc2_w  = (const float*)d_in[8];
    const float* rc2_b  = (const float*)d_in[9];
    const float* rc3_w  = (const float*)d_in[10];
    const float* rc3_b  = (const float*)d_in[11];
    const float* rr1_w  = (const float*)d_in[12];
    const float* rr1_b  = (const float*)d_in[13];
    const float* rr2_w  = (const float*)d_in[14];
    const float* rr2_b  = (const float*)d_in[15];
    const float* rr3_w  = (const float*)d_in[16];
    const float* rr3_b  = (const float*)d_in[17];
    float* out = (float*)d_out;

    int B = in_sizes[0] / 2;       // rows (4194304)
    int NW = B / 128;              // 128 rows per wave
    int block = 256;               // 4 waves per block
    int grid = (NW + 3) / 4;
    rollout_kernel<<<grid, block, 0, stream>>>(
        s_star, s0, fc1_w, fc1_b, fc2_w, fc2_b,
        rc1_w, rc1_b, rc2_w, rc2_b, rc3_w, rc3_b,
        rr1_w, rr1_b, rr2_w, rr2_b, rr3_w, rr3_b,
        out, NW);
}

// Round 21
// 352.573 us; speedup vs baseline: 1.2170x; 1.2170x over previous
//
#include <hip/hip_runtime.h>
#include <hip/hip_fp16.h>

#define DT 0.1f
#define NSTEPS 10
#define SC 2.8853900818f   // 2*log2(e): folded into W1,b1,W2,b2 so D = 2log2e*z

typedef float f4 __attribute__((ext_vector_type(4)));
typedef __fp16 h2 __attribute__((ext_vector_type(2)));
typedef __fp16 h4 __attribute__((ext_vector_type(4)));
typedef int i2 __attribute__((ext_vector_type(2)));

// MFMA builtin exists only in the device pass; host pass just needs to parse.
#if defined(__HIP_DEVICE_COMPILE__)
  #if __has_builtin(__builtin_amdgcn_mfma_f32_16x16x16f16)
    #define MFMA16(A, B, C) __builtin_amdgcn_mfma_f32_16x16x16f16((A), (B), (C), 0, 0, 0)
  #else
    #define MFMA16(A, B, C) __builtin_amdgcn_mfma_f32_16x16x16_f16((A), (B), (C), 0, 0, 0)
  #endif
  #define SQRTF(x) __builtin_amdgcn_sqrtf(x)
#else
  #define MFMA16(A, B, C) ((void)(A), (void)(B), (C))
  #define SQRTF(x) sqrtf(x)
#endif

#define H2C(v) {(__fp16)(v), (__fp16)(v)}

// rcp-free tanh on a 4-f32 accumulator D = 2log2e*z.
//   u = exp2(-|D|) = e^{-2|z|}  (1 trans/value; exact saturation: u->0 -> m=1)
//   |tanh| = (1-u)*Q(u), Q ~= 1/(1+u) deg-5 (trunc err <=5e-5; f16 rounding
//   damped by (1-u) mid-domain and by Q(0)=1 exact at the tail)
//   sign restored bitwise from D.
static __device__ __forceinline__ h4 act_h4(f4 d) {
    int t01 = __builtin_bit_cast(int, __floats2half2_rn(d[0], d[1]));
    int t23 = __builtin_bit_cast(int, __floats2half2_rn(d[2], d[3]));
    __half2 u01h = h2exp2(__builtin_bit_cast(__half2, t01 | 0x80008000));
    __half2 u23h = h2exp2(__builtin_bit_cast(__half2, t23 | 0x80008000));
    h2 u0 = __builtin_bit_cast(h2, u01h);
    h2 u1 = __builtin_bit_cast(h2, u23h);

    const h2 c0 = H2C(1.0f);
    const h2 c1 = H2C(-0.99662f);
    const h2 c2 = H2C(0.95608f);
    const h2 c3 = H2C(-0.77779f);
    const h2 c4 = H2C(0.426008f);
    const h2 c5 = H2C(-0.107658f);
    const h2 one = H2C(1.0f);

    h2 q0 = c5;
    q0 = q0 * u0 + c4;
    q0 = q0 * u0 + c3;
    q0 = q0 * u0 + c2;
    q0 = q0 * u0 + c1;
    q0 = q0 * u0 + c0;
    h2 m0 = (one - u0) * q0;

    h2 q1 = c5;
    q1 = q1 * u1 + c4;
    q1 = q1 * u1 + c3;
    q1 = q1 * u1 + c2;
    q1 = q1 * u1 + c1;
    q1 = q1 * u1 + c0;
    h2 m1 = (one - u1) * q1;

    // sign(tanh) = sign(z) = sign(D): bfi pattern (mask keeps magnitude)
    int r01 = (__builtin_bit_cast(int, m0) & 0x7FFF7FFF) | (t01 & 0x80008000);
    int r23 = (__builtin_bit_cast(int, m1) & 0x7FFF7FFF) | (t23 & 0x80008000);
    i2 pr; pr[0] = r01; pr[1] = r23;
    return __builtin_bit_cast(h4, pr);
}

__global__ void __launch_bounds__(256) rollout_kernel(
    const float* __restrict__ s_star, const float* __restrict__ s0,
    const float* __restrict__ fc1_w, const float* __restrict__ fc1_b,
    const float* __restrict__ fc2_w, const float* __restrict__ fc2_b,
    const float* __restrict__ rc1_w, const float* __restrict__ rc1_b,
    const float* __restrict__ rc2_w, const float* __restrict__ rc2_b,
    const float* __restrict__ rc3_w, const float* __restrict__ rc3_b,
    const float* __restrict__ rr1_w, const float* __restrict__ rr1_b,
    const float* __restrict__ rr2_w, const float* __restrict__ rr2_b,
    const float* __restrict__ rr3_w, const float* __restrict__ rr3_b,
    float* __restrict__ out, int NW)   // NW = B/128 waves
{
    int lane = threadIdx.x & 63;
    int wid  = threadIdx.x >> 6;
    int wave = blockIdx.x * 4 + wid;
    if (wave >= NW) return;

    int col = lane & 15;                // batch column within each 16-row chunk
    int kg  = lane >> 4;                // k-group / chunk ownership 0..3
    int rA  = col;                      // A-fragment row for this lane
    int rowA = wave * 128 + lane;       // set 0 row
    int rowB = rowA + 64;               // set 1 row

    // ---- uniform fused predictor: ah = A @ [s, s_star] + cb ----
    float A[2][4];
    float cb[2];
#pragma unroll
    for (int r = 0; r < 2; ++r) {
#pragma unroll
        for (int c = 0; c < 4; ++c) {
            float a = 0.0f;
#pragma unroll
            for (int j = 0; j < 4; ++j)
                a = fmaf(fc2_w[r * 4 + j], fc1_w[j * 4 + c], a);
            A[r][c] = a;
        }
        float b = fc2_b[r];
#pragma unroll
        for (int j = 0; j < 4; ++j) b = fmaf(fc2_w[r * 4 + j], fc1_b[j], b);
        cb[r] = b;
    }

    // ---- per-lane state, 2 row-sets ----
    float ssx[2], ssy[2], sx[2], sy[2], d0[2], d1[2], ahs0[2], err[2];
    {
        float2 sA = reinterpret_cast<const float2*>(s_star)[rowA];
        float2 sB = reinterpret_cast<const float2*>(s_star)[rowB];
        float2 vA = reinterpret_cast<const float2*>(s0)[rowA];
        float2 vB = reinterpret_cast<const float2*>(s0)[rowB];
        ssx[0] = sA.x; ssy[0] = sA.y; sx[0] = vA.x; sy[0] = vA.y;
        ssx[1] = sB.x; ssy[1] = sB.y; sx[1] = vB.x; sy[1] = vB.y;
    }
#pragma unroll
    for (int s = 0; s < 2; ++s) {
        d0[s] = fmaf(A[0][2], ssx[s], fmaf(A[0][3], ssy[s], cb[0]));
        d1[s] = fmaf(A[1][2], ssx[s], fmaf(A[1][3], ssy[s], cb[1]));
        ahs0[s] = (ssx[s] > 0.5f) ? -1.0f : 1.0f;
        err[s] = 0.0f;
    }

    h4 zero4; zero4[0] = (__fp16)0.0f; zero4[1] = (__fp16)0.0f;
    zero4[2] = (__fp16)0.0f; zero4[3] = (__fp16)0.0f;

    // ---- A1: SC*W1 rows (0-7 rr, 8-15 rc), masked per chunk (loop-invariant) ----
    int jr = rA & 7;
    const float* w1p = (rA < 8) ? rr1_w : rc1_w;
    h4 A1raw;
#pragma unroll
    for (int j = 0; j < 4; ++j) A1raw[j] = (__fp16)(SC * w1p[jr * 4 + j]);
    h4 A1m[4];
#pragma unroll
    for (int q = 0; q < 4; ++q) A1m[q] = (kg == q) ? A1raw : zero4;

    // ---- A2: SC * block-diag(W2rr, W2rc), shared by all chunks ----
    h4 A2;
#pragma unroll
    for (int j = 0; j < 4; ++j) {
        int k = 4 * kg + j;
        float v = 0.0f;
        if (rA < 8) { if (k < 8) v = rr2_w[rA * 8 + k]; }
        else        { if (k >= 8) v = rc2_w[(rA - 8) * 8 + (k - 8)]; }
        A2[j] = (__fp16)(SC * v);
    }

    // ---- A3: per-chunk fragments (chunk q outputs -> rows 4q..4q+3), UNscaled ----
    int qstar = rA >> 2;
    int o = rA & 3;
    h4 A3own;
#pragma unroll
    for (int j = 0; j < 4; ++j) {
        int k = 4 * kg + j;
        float v = 0.0f;
        if (o < 2) { if (k < 8)  v = rr3_w[o * 8 + k]; }
        else       { if (k >= 8) v = rc3_w[(o - 2) * 8 + (k - 8)]; }
        A3own[j] = (__fp16)v;
    }
    h4 A3f[4];
#pragma unroll
    for (int q = 0; q < 4; ++q) A3f[q] = (qstar == q) ? A3own : zero4;

    // ---- C operands (f32; C1/C2 scaled by SC, C3 unscaled) ----
    f4 C1, C2, C3;
#pragma unroll
    for (int j = 0; j < 4; ++j) {
        int r4 = 4 * kg + j;
        C1[j] = SC * ((r4 < 8) ? rr1_b[r4] : rc1_b[r4 - 8]);
        C2[j] = SC * ((r4 < 8) ? rr2_b[r4] : rc2_b[r4 - 8]);
    }
    C3[0] = rr3_b[0]; C3[1] = rr3_b[1]; C3[2] = rc3_b[0]; C3[3] = rc3_b[1];

#pragma unroll 1
    for (int t = 0; t < NSTEPS; ++t) {
        float ah0[2], ah1[2];
        h4 Bown[2];
#pragma unroll
        for (int s = 0; s < 2; ++s) {
            ah0[s] = fmaf(A[0][0], sx[s], fmaf(A[0][1], sy[s], d0[s]));
            ah1[s] = fmaf(A[1][0], sx[s], fmaf(A[1][1], sy[s], d1[s]));
            h2 lo = __builtin_bit_cast(h2, __floats2half2_rn(sx[s], sy[s]));
            h2 hi = __builtin_bit_cast(h2, __floats2half2_rn(ah0[s], ah1[s]));
            Bown[s][0] = lo[0]; Bown[s][1] = lo[1];
            Bown[s][2] = hi[0]; Bown[s][3] = hi[1];
        }

        // L1: 8 independent MFMAs (A-masked, unmasked own-state B)
        h4 B2[2][4];
#pragma unroll
        for (int s = 0; s < 2; ++s) {
#pragma unroll
            for (int q = 0; q < 4; ++q) {
                f4 D1 = MFMA16(A1m[q], Bown[s], C1);
                B2[s][q] = act_h4(D1);
            }
        }

        // L2: 8 independent MFMAs
        h4 B3[2][4];
#pragma unroll
        for (int s = 0; s < 2; ++s) {
#pragma unroll
            for (int q = 0; q < 4; ++q) {
                f4 D2 = MFMA16(A2, B2[s][q], C2);
                B3[s][q] = act_h4(D2);
            }
        }

        // L3: per-set accumulator chain over disjoint row-blocks
#pragma unroll
        for (int s = 0; s < 2; ++s) {
            f4 D3 = MFMA16(A3f[0], B3[s][0], C3);
            D3 = MFMA16(A3f[1], B3[s][1], D3);
            D3 = MFMA16(A3f[2], B3[s][2], D3);
            D3 = MFMA16(A3f[3], B3[s][3], D3);

            float arr0 = D3[0], arr1 = D3[1], ar0 = D3[2], ar1 = D3[3];

            sx[s] = fmaf(DT, ar0, sx[s]);
            sy[s] = fmaf(DT, ar1, sy[s]);

            float dx = ssx[s] - sx[s], dy = ssy[s] - sy[s];
            float n1 = fmaf(dx, dx, dy * dy);
            float ux = arr0 - ar0, uy = arr1 - ar1;
            float n2 = fmaf(ux, ux, uy * uy);
            float vx = ahs0[s] - ah0[s];
            float n3 = fmaf(vx, vx, ah1[s] * ah1[s]);

            err[s] = err[s] + SQRTF(n1);
            err[s] = fmaf(0.1f, SQRTF(n2), err[s]);
            err[s] = err[s] + SQRTF(n3);
        }
    }

    out[rowA] = err[0];
    out[rowB] = err[1];
}

extern "C" void kernel_launch(void* const* d_in, const int* in_sizes, int n_in,
                              void* d_out, int out_size, void* d_ws, size_t ws_size,
                              hipStream_t stream) {
    const float* s_star = (const float*)d_in[0];
    const float* s0     = (const float*)d_in[1];
    const float* fc1_w  = (const float*)d_in[2];
    const float* fc1_b  = (const float*)d_in[3];
    const float* fc2_w  = (const float*)d_in[4];
    const float* fc2_b  = (const float*)d_in[5];
    const float* rc1_w  = (const float*)d_in[6];
    const float* rc1_b  = (const float*)d_in[7];
    const float* rc2_w  = (const float*)d_in[8];
    const float* rc2_b  = (const float*)d_in[9];
    const float* rc3_w  = (const float*)d_in[10];
    const float* rc3_b  = (const float*)d_in[11];
    const float* rr1_w  = (const float*)d_in[12];
    const float* rr1_b  = (const float*)d_in[13];
    const float* rr2_w  = (const float*)d_in[14];
    const float* rr2_b  = (const float*)d_in[15];
    const float* rr3_w  = (const float*)d_in[16];
    const float* rr3_b  = (const float*)d_in[17];
    float* out = (float*)d_out;

    int B = in_sizes[0] / 2;       // rows (4194304)
    int NW = B / 128;              // 128 rows per wave
    int block = 256;               // 4 waves per block
    int grid = (NW + 3) / 4;
    rollout_kernel<<<grid, block, 0, stream>>>(
        s_star, s0, fc1_w, fc1_b, fc2_w, fc2_b,
        rc1_w, rc1_b, rc2_w, rc2_b, rc3_w, rc3_b,
        rr1_w, rr1_b, rr2_w, rr2_b, rr3_w, rr3_b,
        out, NW);
}

// Round 22
// 335.939 us; speedup vs baseline: 1.2773x; 1.0495x over previous
//
#include <hip/hip_runtime.h>
#include <hip/hip_fp16.h>

#define DT 0.1f
#define NSTEPS 10

typedef float f4 __attribute__((ext_vector_type(4)));
typedef __fp16 h2 __attribute__((ext_vector_type(2)));
typedef __fp16 h4 __attribute__((ext_vector_type(4)));

// MFMA builtin exists only in the device pass; host pass just needs to parse.
#if defined(__HIP_DEVICE_COMPILE__)
  #if __has_builtin(__builtin_amdgcn_mfma_f32_16x16x16f16)
    #define MFMA16(A, B, C) __builtin_amdgcn_mfma_f32_16x16x16f16((A), (B), (C), 0, 0, 0)
  #else
    #define MFMA16(A, B, C) __builtin_amdgcn_mfma_f32_16x16x16_f16((A), (B), (C), 0, 0, 0)
  #endif
  #define SQRTF(x) __builtin_amdgcn_sqrtf(x)
#else
  #define MFMA16(A, B, C) ((void)(A), (void)(B), (C))
  #define SQRTF(x) sqrtf(x)
#endif

// Packed-f16 tanh (validated R10-R17): tanh(x) = 1 - 2/(exp2(k*x)+1).
// NaN-free saturation in f16.
static __device__ __forceinline__ __half2 tanh2(__half2 z) {
    const __half2 kk   = __float2half2_rn(2.8853900818f);
    const __half2 one  = __float2half2_rn(1.0f);
    const __half2 mtwo = __float2half2_rn(-2.0f);
    __half2 e = h2exp2(__hmul2(z, kk));
    __half2 r = h2rcp(__hadd2(e, one));
    return __hfma2(r, mtwo, one);
}

// tanh on a 4-f32 MFMA accumulator -> 4 halves, laid out ready as the next
// MFMA's B operand (D row index == next B k index, same lane/reg structure).
static __device__ __forceinline__ h4 act_h4(f4 d) {
    __half2 a = __floats2half2_rn(d[0], d[1]);   // low = d[0]
    __half2 b = __floats2half2_rn(d[2], d[3]);
    h2 ta = __builtin_bit_cast(h2, tanh2(a));
    h2 tb = __builtin_bit_cast(h2, tanh2(b));
    h4 r;
    r[0] = ta[0]; r[1] = ta[1]; r[2] = tb[0]; r[3] = tb[1];
    return r;
}

__global__ void __launch_bounds__(256) rollout_kernel(
    const float* __restrict__ s_star, const float* __restrict__ s0,
    const float* __restrict__ fc1_w, const float* __restrict__ fc1_b,
    const float* __restrict__ fc2_w, const float* __restrict__ fc2_b,
    const float* __restrict__ rc1_w, const float* __restrict__ rc1_b,
    const float* __restrict__ rc2_w, const float* __restrict__ rc2_b,
    const float* __restrict__ rc3_w, const float* __restrict__ rc3_b,
    const float* __restrict__ rr1_w, const float* __restrict__ rr1_b,
    const float* __restrict__ rr2_w, const float* __restrict__ rr2_b,
    const float* __restrict__ rr3_w, const float* __restrict__ rr3_b,
    float* __restrict__ out, int NW)   // NW = B/128 waves
{
    int lane = threadIdx.x & 63;
    int wid  = threadIdx.x >> 6;
    int wave = blockIdx.x * 4 + wid;
    if (wave >= NW) return;

    int col = lane & 15;                // batch column within each 16-row chunk
    int kg  = lane >> 4;                // k-group / chunk ownership 0..3
    int rA  = col;                      // A-fragment row for this lane
    int rowA = wave * 128 + lane;       // set 0 row
    int rowB = rowA + 64;               // set 1 row

    // ---- uniform fused predictor: ah = A @ [s, s_star] + cb ----
    float A[2][4];
    float cb[2];
#pragma unroll
    for (int r = 0; r < 2; ++r) {
#pragma unroll
        for (int c = 0; c < 4; ++c) {
            float a = 0.0f;
#pragma unroll
            for (int j = 0; j < 4; ++j)
                a = fmaf(fc2_w[r * 4 + j], fc1_w[j * 4 + c], a);
            A[r][c] = a;
        }
        float b = fc2_b[r];
#pragma unroll
        for (int j = 0; j < 4; ++j) b = fmaf(fc2_w[r * 4 + j], fc1_b[j], b);
        cb[r] = b;
    }

    // ---- per-lane state, 2 row-sets ----
    float ssx[2], ssy[2], sx[2], sy[2], d0[2], d1[2], ahs0[2], err[2];
    {
        float2 sA = reinterpret_cast<const float2*>(s_star)[rowA];
        float2 sB = reinterpret_cast<const float2*>(s_star)[rowB];
        float2 vA = reinterpret_cast<const float2*>(s0)[rowA];
        float2 vB = reinterpret_cast<const float2*>(s0)[rowB];
        ssx[0] = sA.x; ssy[0] = sA.y; sx[0] = vA.x; sy[0] = vA.y;
        ssx[1] = sB.x; ssy[1] = sB.y; sx[1] = vB.x; sy[1] = vB.y;
    }
#pragma unroll
    for (int s = 0; s < 2; ++s) {
        d0[s] = fmaf(A[0][2], ssx[s], fmaf(A[0][3], ssy[s], cb[0]));
        d1[s] = fmaf(A[1][2], ssx[s], fmaf(A[1][3], ssy[s], cb[1]));
        ahs0[s] = (ssx[s] > 0.5f) ? -1.0f : 1.0f;
        err[s] = 0.0f;
    }

    h4 zero4; zero4[0] = (__fp16)0.0f; zero4[1] = (__fp16)0.0f;
    zero4[2] = (__fp16)0.0f; zero4[3] = (__fp16)0.0f;

    // ---- A1: raw W1 rows (0-7 rr, 8-15 rc), masked per chunk (loop-invariant) ----
    int jr = rA & 7;
    const float* w1p = (rA < 8) ? rr1_w : rc1_w;
    h4 A1raw;
#pragma unroll
    for (int j = 0; j < 4; ++j) A1raw[j] = (__fp16)w1p[jr * 4 + j];
    h4 A1m[4];
#pragma unroll
    for (int q = 0; q < 4; ++q) A1m[q] = (kg == q) ? A1raw : zero4;

    // ---- A2: block-diag(W2rr, W2rc), shared by all chunks ----
    h4 A2;
#pragma unroll
    for (int j = 0; j < 4; ++j) {
        int k = 4 * kg + j;
        float v = 0.0f;
        if (rA < 8) { if (k < 8) v = rr2_w[rA * 8 + k]; }
        else        { if (k >= 8) v = rc2_w[(rA - 8) * 8 + (k - 8)]; }
        A2[j] = (__fp16)v;
    }

    // ---- A3: per-chunk fragments (chunk q outputs -> rows 4q..4q+3) ----
    int qstar = rA >> 2;
    int o = rA & 3;
    h4 A3own;
#pragma unroll
    for (int j = 0; j < 4; ++j) {
        int k = 4 * kg + j;
        float v = 0.0f;
        if (o < 2) { if (k < 8)  v = rr3_w[o * 8 + k]; }
        else       { if (k >= 8) v = rc3_w[(o - 2) * 8 + (k - 8)]; }
        A3own[j] = (__fp16)v;
    }
    h4 A3f[4];
#pragma unroll
    for (int q = 0; q < 4; ++q) A3f[q] = (qstar == q) ? A3own : zero4;

    // ---- C operands (f32; C/D row = 4*kg+reg, col = lane&15) ----
    f4 C1, C2, C3;
#pragma unroll
    for (int j = 0; j < 4; ++j) {
        int r4 = 4 * kg + j;
        C1[j] = (r4 < 8) ? rr1_b[r4] : rc1_b[r4 - 8];
        C2[j] = (r4 < 8) ? rr2_b[r4] : rc2_b[r4 - 8];
    }
    C3[0] = rr3_b[0]; C3[1] = rr3_b[1]; C3[2] = rc3_b[0]; C3[3] = rc3_b[1];

#pragma unroll 1
    for (int t = 0; t < NSTEPS; ++t) {
        float ah0[2], ah1[2];
        h4 Bown[2];
#pragma unroll
        for (int s = 0; s < 2; ++s) {
            ah0[s] = fmaf(A[0][0], sx[s], fmaf(A[0][1], sy[s], d0[s]));
            ah1[s] = fmaf(A[1][0], sx[s], fmaf(A[1][1], sy[s], d1[s]));
            h2 lo = __builtin_bit_cast(h2, __floats2half2_rn(sx[s], sy[s]));
            h2 hi = __builtin_bit_cast(h2, __floats2half2_rn(ah0[s], ah1[s]));
            Bown[s][0] = lo[0]; Bown[s][1] = lo[1];
            Bown[s][2] = hi[0]; Bown[s][3] = hi[1];
        }

        // L1: 8 independent MFMAs (A-masked, unmasked own-state B)
        h4 B2[2][4];
#pragma unroll
        for (int s = 0; s < 2; ++s) {
#pragma unroll
            for (int q = 0; q < 4; ++q) {
                f4 D1 = MFMA16(A1m[q], Bown[s], C1);
                B2[s][q] = act_h4(D1);
            }
        }

        // L2: 8 independent MFMAs
        h4 B3[2][4];
#pragma unroll
        for (int s = 0; s < 2; ++s) {
#pragma unroll
            for (int q = 0; q < 4; ++q) {
                f4 D2 = MFMA16(A2, B2[s][q], C2);
                B3[s][q] = act_h4(D2);
            }
        }

        // L3: per-set accumulator chain over disjoint row-blocks
#pragma unroll
        for (int s = 0; s < 2; ++s) {
            f4 D3 = MFMA16(A3f[0], B3[s][0], C3);
            D3 = MFMA16(A3f[1], B3[s][1], D3);
            D3 = MFMA16(A3f[2], B3[s][2], D3);
            D3 = MFMA16(A3f[3], B3[s][3], D3);

            float arr0 = D3[0], arr1 = D3[1], ar0 = D3[2], ar1 = D3[3];

            sx[s] = fmaf(DT, ar0, sx[s]);
            sy[s] = fmaf(DT, ar1, sy[s]);

            float dx = ssx[s] - sx[s], dy = ssy[s] - sy[s];
            float n1 = fmaf(dx, dx, dy * dy);
            float ux = arr0 - ar0, uy = arr1 - ar1;
            float n2 = fmaf(ux, ux, uy * uy);
            float vx = ahs0[s] - ah0[s];
            float n3 = fmaf(vx, vx, ah1[s] * ah1[s]);

            err[s] = err[s] + SQRTF(n1);
            err[s] = fmaf(0.1f, SQRTF(n2), err[s]);
            err[s] = err[s] + SQRTF(n3);
        }
    }

    out[rowA] = err[0];
    out[rowB] = err[1];
}

extern "C" void kernel_launch(void* const* d_in, const int* in_sizes, int n_in,
                              void* d_out, int out_size, void* d_ws, size_t ws_size,
                              hipStream_t stream) {
    const float* s_star = (const float*)d_in[0];
    const float* s0     = (const float*)d_in[1];
    const float* fc1_w  = (const float*)d_in[2];
    const float* fc1_b  = (const float*)d_in[3];
    const float* fc2_w  = (const float*)d_in[4];
    const float* fc2_b  = (const float*)d_in[5];
    const float* rc1_w  = (const float*)d_in[6];
    const float* rc1_b  = (const float*)d_in[7];
    const float* rc2_w  = (const float*)d_in[8];
    const float* rc2_b  = (const float*)d_in[9];
    const float* rc3_w  = (const float*)d_in[10];
    const float* rc3_b  = (const float*)d_in[11];
    const float* rr1_w  = (const float*)d_in[12];
    const float* rr1_b  = (const float*)d_in[13];
    const float* rr2_w  = (const float*)d_in[14];
    const float* rr2_b  = (const float*)d_in[15];
    const float* rr3_w  = (const float*)d_in[16];
    const float* rr3_b  = (const float*)d_in[17];
    float* out = (float*)d_out;

    int B = in_sizes[0] / 2;       // rows (4194304)
    int NW = B / 128;              // 128 rows per wave
    int block = 256;               // 4 waves per block
    int grid = (NW + 3) / 4;
    rollout_kernel<<<grid, block, 0, stream>>>(
        s_star, s0, fc1_w, fc1_b, fc2_w, fc2_b,
        rc1_w, rc1_b, rc2_w, rc2_b, rc3_w, rc3_b,
        rr1_w, rr1_b, rr2_w, rr2_b, rr3_w, rr3_b,
        out, NW);
}